// Round 5
// baseline (166.895 us; speedup 1.0000x reference)
//
#include <hip/hip_runtime.h>
#include <cstddef>
#include <math.h>

#define BD 8
#define TD 256
#define SD 256
#define HD 512
#define K2F 2.885390081777927f    // 2*log2(e): arg of exp2 for e^(2x)

#define EXP2(x) __builtin_amdgcn_exp2f(x)
#define RCP(x)  __builtin_amdgcn_rcpf(x)

typedef __attribute__((ext_vector_type(8))) short short8;
typedef __attribute__((ext_vector_type(4))) float float4v;
typedef unsigned short u16;

__device__ __forceinline__ u16 bf_hi(float x) {
    union { float f; unsigned u; } v; v.f = x;
    unsigned r = v.u + 0x7fff + ((v.u >> 16) & 1);
    return (u16)(r >> 16);
}
__device__ __forceinline__ float bf_tof(u16 h) {
    union { float f; unsigned u; } v; v.u = ((unsigned)h) << 16;
    return v.f;
}

// global -> LDS direct DMA, 16 B per lane; lds base must be wave-uniform.
#define GL2LDS(g, l) __builtin_amdgcn_global_load_lds( \
    (const __attribute__((address_space(1))) void*)(g), \
    (__attribute__((address_space(3))) void*)(l), 16, 0, 0)

// ---------------- convert: fp32 -> split-bf16 planes ----------------
// A = [enc(2048 rows); qry(2048 rows)] x 512 -> Ah, Al
// B = [W_h(512 rows);  W_s(512 rows)]  x 512 -> Bh, Bl
__global__ __launch_bounds__(256) void convert_kernel(
    const float* __restrict__ enc, const float* __restrict__ qry,
    const float* __restrict__ Wh,  const float* __restrict__ Ws,
    u16* __restrict__ Ah, u16* __restrict__ Al,
    u16* __restrict__ Bh, u16* __restrict__ Bl)
{
    const int bid = blockIdx.x, tid = threadIdx.x;
    const float* src; u16 *dh, *dl; size_t i4;
    if (bid < 1024)      { src = enc; dh = Ah;                     dl = Al;                     i4 = (size_t)bid * 256 + tid; }
    else if (bid < 2048) { src = qry; dh = Ah + (size_t)2048*512;  dl = Al + (size_t)2048*512;  i4 = (size_t)(bid-1024)*256 + tid; }
    else if (bid < 2304) { src = Wh;  dh = Bh;                     dl = Bl;                     i4 = (size_t)(bid-2048)*256 + tid; }
    else                 { src = Ws;  dh = Bh + (size_t)512*512;   dl = Bl + (size_t)512*512;   i4 = (size_t)(bid-2304)*256 + tid; }
    float4 x = ((const float4*)src)[i4];
    u16 h0 = bf_hi(x.x), h1 = bf_hi(x.y), h2 = bf_hi(x.z), h3 = bf_hi(x.w);
    ushort4 hv = make_ushort4(h0, h1, h2, h3);
    ushort4 lv = make_ushort4(bf_hi(x.x - bf_tof(h0)), bf_hi(x.y - bf_tof(h1)),
                              bf_hi(x.z - bf_tof(h2)), bf_hi(x.w - bf_tof(h3)));
    ((ushort4*)dh)[i4] = hv;
    ((ushort4*)dl)[i4] = lv;
}

// ---------------- proj: split-bf16 MFMA GEMM, DMA-staged ----------------
// Blocks y<32: enc rows -> encT (B,H,S) * K2F.  y>=32: qry rows -> qryf (B,T,H) * K2F.
// 64x64 tile, BK=128 (4 steps), LDS tiles 64x128 bf16 per plane, XOR chunk swizzle.
__global__ __launch_bounds__(256) void proj_kernel(
    const u16* __restrict__ Ahg, const u16* __restrict__ Alg,
    const u16* __restrict__ Bhg, const u16* __restrict__ Blg,
    float* __restrict__ encT, float* __restrict__ qryf)
{
    __shared__ u16 lds[4 * 64 * 128];   // Ah | Al | Bh | Bl
    u16* LAh = lds;
    u16* LAl = lds + 8192;
    u16* LBh = lds + 16384;
    u16* LBl = lds + 24576;

    const int tid = threadIdx.x;
    const int l = tid & 63, w = tid >> 6;
    const int rf = l & 15, q = l >> 4;
    const int my = blockIdx.y;
    const bool isq = my >= 32;
    const int m0 = my * 64;                 // row in stacked A (0..4095)
    const int n0 = blockIdx.x * 64;         // output col
    const int brow0 = (isq ? 512 : 0) + n0; // row in stacked B

    const int srsub = l >> 4;               // staging: sub-row 0..3
    const int cs    = l & 15;               // staging: chunk slot 0..15

    float4v acc[4] = {{0,0,0,0},{0,0,0,0},{0,0,0,0},{0,0,0,0}};

    for (int ks = 0; ks < 4; ++ks) {
        const int k0 = ks * 128;
        __syncthreads();                    // prior step's frag reads done
        #pragma unroll
        for (int i = 0; i < 4; ++i) {
            const int r = w * 16 + i * 4 + srsub;   // tile row this lane fetches
            const int g = cs ^ (r & 15);            // swizzled source chunk
            const size_t gofA = (size_t)(m0 + r) * HD + k0 + g * 8;
            const size_t gofB = (size_t)(brow0 + r) * HD + k0 + g * 8;
            const int lb = (w * 16 + i * 4) * 128;  // wave-uniform LDS base (elems)
            GL2LDS(Ahg + gofA, LAh + lb);
            GL2LDS(Alg + gofA, LAl + lb);
            GL2LDS(Bhg + gofB, LBh + lb);
            GL2LDS(Blg + gofB, LBl + lb);
        }
        __syncthreads();                    // drains vmcnt, staging visible

        short8 ah[4], al[4];
        #pragma unroll
        for (int kc = 0; kc < 4; ++kc) {
            const int off = (w * 16 + rf) * 128 + ((kc * 4 + q) ^ rf) * 8;
            ah[kc] = *(const short8*)&LAh[off];
            al[kc] = *(const short8*)&LAl[off];
        }
        #pragma unroll
        for (int c = 0; c < 4; ++c) {
            #pragma unroll
            for (int kc = 0; kc < 4; ++kc) {
                const int off = (c * 16 + rf) * 128 + ((kc * 4 + q) ^ rf) * 8;
                short8 bh = *(const short8*)&LBh[off];
                short8 bl = *(const short8*)&LBl[off];
                acc[c] = __builtin_amdgcn_mfma_f32_16x16x32_bf16(ah[kc], bh, acc[c], 0, 0, 0);
                acc[c] = __builtin_amdgcn_mfma_f32_16x16x32_bf16(ah[kc], bl, acc[c], 0, 0, 0);
                acc[c] = __builtin_amdgcn_mfma_f32_16x16x32_bf16(al[kc], bh, acc[c], 0, 0, 0);
            }
        }
    }

    // Epilogue: C tile (m-local = w*16 + q*4 + r, n-local = c*16 + rf) — R4-verified mapping
    if (!isq) {
        const int b  = m0 >> 8;
        const int sb = (m0 & 255) + w * 16 + q * 4;
        float* base = encT + (size_t)b * HD * SD + sb;
        #pragma unroll
        for (int c = 0; c < 4; ++c) {
            float4 o = make_float4(acc[c][0]*K2F, acc[c][1]*K2F, acc[c][2]*K2F, acc[c][3]*K2F);
            *(float4*)(base + (size_t)(n0 + c * 16 + rf) * SD) = o;
        }
    } else {
        const int mrow = (m0 - 2048) + w * 16 + q * 4;
        #pragma unroll
        for (int c = 0; c < 4; ++c)
            #pragma unroll
            for (int r = 0; r < 4; ++r)
                qryf[(size_t)(mrow + r) * HD + n0 + c * 16 + rf] = acc[c][r] * K2F;
    }
}

// ---------------- attn: lane owns 4 consecutive s; wave = (t, j-half) ----------------
// score'_s = -2 * sum_j v_j / (1 + exp2(encT[j][s] + q[j][t]))
__global__ __launch_bounds__(512) void attn_kernel(
    const float* __restrict__ enc,     // (B,S,H) raw
    const float* __restrict__ encT,    // (B,H,S) projected * K2F
    const float* __restrict__ qry_f,   // (B,T,H) projected * K2F
    const float* __restrict__ v,       // (H)
    const int*   __restrict__ lens,    // (B)
    float* __restrict__ out)           // (B,T,H)
{
    __shared__ float qls[HD * 4];      // [j][t] 8 KB
    __shared__ float pls[8 * 256];     // per-wave partial scores 8 KB
    __shared__ float wls[4 * 256];     // per-t weights 4 KB

    const int blk = blockIdx.x;        // 0..511
    const int b   = blk >> 6;
    const int t0  = (blk & 63) * 4;
    const int tid = threadIdx.x;
    const int w   = tid >> 6;          // wave 0..7
    const int l   = tid & 63;
    const int tw  = w & 3;             // t index within group
    const int jh  = w >> 2;            // j half 0/1

    {   // stage q transposed: qls[j*4 + t]
        const float* qf = qry_f + ((size_t)b * TD + t0) * HD;
        #pragma unroll
        for (int t = 0; t < 4; ++t)
            qls[tid * 4 + t] = qf[(size_t)t * HD + tid];
    }
    __syncthreads();

    // ---- scores: lane owns s = 4l..4l+3, wave covers j in [jh*256, jh*256+256) ----
    float a0 = 0.f, a1 = 0.f, a2 = 0.f, a3 = 0.f;
    {
        const float* ep = encT + (size_t)b * HD * SD + (size_t)(jh * 256) * SD + l * 4;
        const float* vp = v + jh * 256;
        const float* qp = &qls[(jh * 256) * 4 + tw];
        #pragma unroll 4
        for (int j = 0; j < 256; ++j) {
            float4 e = *(const float4*)(ep + (size_t)j * SD);  // coalesced 1 KB/wave
            float qw = qp[j * 4];                              // wave-uniform broadcast
            float vj = vp[j];                                  // block-uniform -> s_load
            a0 = fmaf(vj, RCP(1.0f + EXP2(e.x + qw)), a0);
            a1 = fmaf(vj, RCP(1.0f + EXP2(e.y + qw)), a1);
            a2 = fmaf(vj, RCP(1.0f + EXP2(e.z + qw)), a2);
            a3 = fmaf(vj, RCP(1.0f + EXP2(e.w + qw)), a3);
        }
    }
    *(float4*)&pls[w * 256 + l * 4] = make_float4(a0, a1, a2, a3);
    __syncthreads();

    // ---- combine halves + masked softmax (waves w and w+4 duplicate — identical bits) ----
    float4 p0 = *(const float4*)&pls[tw * 256 + l * 4];
    float4 p1 = *(const float4*)&pls[(tw + 4) * 256 + l * 4];
    const int len = lens[b];
    const int s0 = l * 4;
    float sc0 = (s0 + 0 < len) ? -2.0f * (p0.x + p1.x) : -INFINITY;
    float sc1 = (s0 + 1 < len) ? -2.0f * (p0.y + p1.y) : -INFINITY;
    float sc2 = (s0 + 2 < len) ? -2.0f * (p0.z + p1.z) : -INFINITY;
    float sc3 = (s0 + 3 < len) ? -2.0f * (p0.w + p1.w) : -INFINITY;

    float mx = fmaxf(fmaxf(sc0, sc1), fmaxf(sc2, sc3));
    #pragma unroll
    for (int off = 32; off; off >>= 1) mx = fmaxf(mx, __shfl_xor(mx, off));
    float e0 = __expf(sc0 - mx);       // exp(-inf) = 0 handles masking
    float e1 = __expf(sc1 - mx);
    float e2 = __expf(sc2 - mx);
    float e3 = __expf(sc3 - mx);
    float sum = e0 + e1 + e2 + e3;
    #pragma unroll
    for (int off = 32; off; off >>= 1) sum += __shfl_xor(sum, off);
    const float inv = RCP(sum);
    *(float4*)&wls[tw * 256 + l * 4] = make_float4(e0*inv, e1*inv, e2*inv, e3*inv);
    __syncthreads();

    // ---- AV: 128 threads per t; thread owns h-float4 ----
    const int tv = tid >> 7;           // 0..3, wave-uniform
    const int hl = (tid & 127) * 4;
    const float* eb = enc + (size_t)b * SD * HD + hl;
    const float* wp = &wls[tv * 256];
    float4 o = {0, 0, 0, 0};
    #pragma unroll 4
    for (int s = 0; s < SD; ++s) {
        const float ww = wp[s];        // broadcast
        const float4 ev = *(const float4*)(eb + (size_t)s * HD);
        o.x = fmaf(ww, ev.x, o.x);
        o.y = fmaf(ww, ev.y, o.y);
        o.z = fmaf(ww, ev.z, o.z);
        o.w = fmaf(ww, ev.w, o.w);
    }
    *(float4*)(out + ((size_t)b * TD + t0 + tv) * HD + hl) = o;
}

extern "C" void kernel_launch(void* const* d_in, const int* in_sizes, int n_in,
                              void* d_out, int out_size, void* d_ws, size_t ws_size,
                              hipStream_t stream) {
    const float* query = (const float*)d_in[0];
    const float* enc   = (const float*)d_in[1];
    const int*   lens  = (const int*)d_in[2];
    const float* W_h   = (const float*)d_in[3];
    const float* W_s   = (const float*)d_in[4];
    const float* v     = (const float*)d_in[5];
    float* out = (float*)d_out;

    char* ws = (char*)d_ws;
    float* encT = (float*)(ws);                       // 4 MB (B,H,S)
    float* qryf = (float*)(ws + ((size_t)4  << 20));  // 4 MB (B,T,H)
    u16*   Ah   = (u16*)  (ws + ((size_t)8  << 20));  // 4 MB (4096,512)
    u16*   Al   = (u16*)  (ws + ((size_t)12 << 20));  // 4 MB
    u16*   Bh   = (u16*)  (ws + ((size_t)16 << 20));  // 1 MB (1024,512)
    u16*   Bl   = (u16*)  (ws + ((size_t)17 << 20));  // 1 MB

    convert_kernel<<<2560, 256, 0, stream>>>(enc, query, W_h, W_s, Ah, Al, Bh, Bl);

    dim3 pgrid(HD / 64, 64);
    proj_kernel<<<pgrid, 256, 0, stream>>>(Ah, Al, Bh, Bl, encT, qryf);

    attn_kernel<<<BD * (TD / 4), 512, 0, stream>>>(enc, encT, qryf, v, lens, out);
}

// Round 6
// 149.617 us; speedup vs baseline: 1.1155x; 1.1155x over previous
//
#include <hip/hip_runtime.h>
#include <cstddef>
#include <math.h>

#define BD 8
#define TD 256
#define SD 256
#define HD 512
#define K2F 2.885390081777927f    // 2*log2(e): arg of exp2 for e^(2x)

#define EXP2(x) __builtin_amdgcn_exp2f(x)
#define RCP(x)  __builtin_amdgcn_rcpf(x)

typedef __attribute__((ext_vector_type(8))) short short8;
typedef __attribute__((ext_vector_type(4))) float float4v;
typedef unsigned short u16;

__device__ __forceinline__ u16 bf_hi(float x) {
    union { float f; unsigned u; } v; v.f = x;
    unsigned r = v.u + 0x7fff + ((v.u >> 16) & 1);
    return (u16)(r >> 16);
}
__device__ __forceinline__ float bf_tof(u16 h) {
    union { float f; unsigned u; } v; v.u = ((unsigned)h) << 16;
    return v.f;
}

// ---------------- convert: fp32 -> split-bf16 planes ----------------
__global__ __launch_bounds__(256) void convert_kernel(
    const float* __restrict__ enc, const float* __restrict__ qry,
    const float* __restrict__ Wh,  const float* __restrict__ Ws,
    u16* __restrict__ Ah, u16* __restrict__ Al,
    u16* __restrict__ Bh, u16* __restrict__ Bl)
{
    const int bid = blockIdx.x, tid = threadIdx.x;
    const float* src; u16 *dh, *dl; size_t i4;
    if (bid < 1024)      { src = enc; dh = Ah;                    dl = Al;                    i4 = (size_t)bid * 256 + tid; }
    else if (bid < 2048) { src = qry; dh = Ah + (size_t)2048*512; dl = Al + (size_t)2048*512; i4 = (size_t)(bid-1024)*256 + tid; }
    else if (bid < 2304) { src = Wh;  dh = Bh;                    dl = Bl;                    i4 = (size_t)(bid-2048)*256 + tid; }
    else                 { src = Ws;  dh = Bh + (size_t)512*512;  dl = Bl + (size_t)512*512;  i4 = (size_t)(bid-2304)*256 + tid; }
    float4 x = ((const float4*)src)[i4];
    u16 h0 = bf_hi(x.x), h1 = bf_hi(x.y), h2 = bf_hi(x.z), h3 = bf_hi(x.w);
    ushort4 hv = make_ushort4(h0, h1, h2, h3);
    ushort4 lv = make_ushort4(bf_hi(x.x - bf_tof(h0)), bf_hi(x.y - bf_tof(h1)),
                              bf_hi(x.z - bf_tof(h2)), bf_hi(x.w - bf_tof(h3)));
    ((ushort4*)dh)[i4] = hv;
    ((ushort4*)dl)[i4] = lv;
}

// ---------------- proj: split-bf16 MFMA GEMM, VGPR-staged (R4 flow) ----------------
// Blocks y<32: enc rows -> encT (B,H,S)*K2F.  y>=32: qry rows -> qryf (B,T,H)*K2F.
// 64x64 tile, BK=32 (16 steps), stride-40 LDS, wave owns 32x32 C (2x2 MFMA tiles).
#define LSTR 40
__global__ __launch_bounds__(256) void proj_kernel(
    const u16* __restrict__ Ahg, const u16* __restrict__ Alg,
    const u16* __restrict__ Bhg, const u16* __restrict__ Blg,
    float* __restrict__ encT, float* __restrict__ qryf)
{
    __shared__ u16 LAh[64*LSTR], LAl[64*LSTR], LBh[64*LSTR], LBl[64*LSTR]; // 20 KB

    const int tid = threadIdx.x;
    const int l = tid & 63, w = tid >> 6;
    const int rf = l & 15, q = l >> 4;
    const int my = blockIdx.y;
    const bool isq = my >= 32;
    const int m0 = my * 64;                 // row in stacked A (0..4095)
    const int n0 = blockIdx.x * 64;
    const int brow0 = (isq ? 512 : 0) + n0; // row in stacked B

    const int srow = tid >> 2;              // staging row 0..63
    const int scol = (tid & 3) * 8;         // staging col 0,8,16,24
    const u16* pAh = Ahg + (size_t)(m0 + srow) * HD + scol;
    const u16* pAl = Alg + (size_t)(m0 + srow) * HD + scol;
    const u16* pBh = Bhg + (size_t)(brow0 + srow) * HD + scol;
    const u16* pBl = Blg + (size_t)(brow0 + srow) * HD + scol;

    const int mi = (w & 1) * 32, ni = (w >> 1) * 32;

    float4v acc[2][2] = {{{0,0,0,0},{0,0,0,0}},{{0,0,0,0},{0,0,0,0}}};

    short8 rah = *(const short8*)pAh;
    short8 ral = *(const short8*)pAl;
    short8 rbh = *(const short8*)pBh;
    short8 rbl = *(const short8*)pBl;

    for (int ks = 0; ks < 16; ++ks) {
        if (ks) __syncthreads();
        *(short8*)&LAh[srow * LSTR + scol] = rah;
        *(short8*)&LAl[srow * LSTR + scol] = ral;
        *(short8*)&LBh[srow * LSTR + scol] = rbh;
        *(short8*)&LBl[srow * LSTR + scol] = rbl;
        __syncthreads();
        if (ks + 1 < 16) {
            const int ko = (ks + 1) * 32;
            rah = *(const short8*)(pAh + ko);
            ral = *(const short8*)(pAl + ko);
            rbh = *(const short8*)(pBh + ko);
            rbl = *(const short8*)(pBl + ko);
        }
        short8 ah[2], al[2], bh[2], bl[2];
        #pragma unroll
        for (int i = 0; i < 2; ++i) {
            ah[i] = *(const short8*)&LAh[(mi + i * 16 + rf) * LSTR + q * 8];
            al[i] = *(const short8*)&LAl[(mi + i * 16 + rf) * LSTR + q * 8];
            bh[i] = *(const short8*)&LBh[(ni + i * 16 + rf) * LSTR + q * 8];
            bl[i] = *(const short8*)&LBl[(ni + i * 16 + rf) * LSTR + q * 8];
        }
        #pragma unroll
        for (int i = 0; i < 2; ++i)
            #pragma unroll
            for (int j = 0; j < 2; ++j) {
                acc[i][j] = __builtin_amdgcn_mfma_f32_16x16x32_bf16(ah[i], bh[j], acc[i][j], 0, 0, 0);
                acc[i][j] = __builtin_amdgcn_mfma_f32_16x16x32_bf16(ah[i], bl[j], acc[i][j], 0, 0, 0);
                acc[i][j] = __builtin_amdgcn_mfma_f32_16x16x32_bf16(al[i], bh[j], acc[i][j], 0, 0, 0);
            }
    }

    // Epilogue: m-local = mi + i*16 + q*4 + r, n-local = ni + j*16 + rf (R4-verified)
    if (!isq) {
        const int b  = m0 >> 8;
        const int sb = (m0 & 255) + mi + q * 4;
        float* base = encT + (size_t)b * HD * SD;
        #pragma unroll
        for (int i = 0; i < 2; ++i)
            #pragma unroll
            for (int j = 0; j < 2; ++j) {
                float4 o = make_float4(acc[i][j][0]*K2F, acc[i][j][1]*K2F,
                                       acc[i][j][2]*K2F, acc[i][j][3]*K2F);
                *(float4*)(base + (size_t)(n0 + ni + j * 16 + rf) * SD + sb + i * 16) = o;
            }
    } else {
        const int mrow = (m0 - 2048) + mi + q * 4;
        #pragma unroll
        for (int i = 0; i < 2; ++i)
            #pragma unroll
            for (int j = 0; j < 2; ++j)
                #pragma unroll
                for (int r = 0; r < 4; ++r)
                    qryf[(size_t)(mrow + i * 16 + r) * HD + n0 + ni + j * 16 + rf] = acc[i][j][r] * K2F;
    }
}

// ---------------- attn: wave owns j-slice, computes ALL 4 t per e-load ----------------
// score'_s(t) = -2 * sum_j v_j / (1 + exp2(encT[j][s] + q[j][t]))
__global__ __launch_bounds__(512) void attn_kernel(
    const float* __restrict__ enc,     // (B,S,H) raw
    const float* __restrict__ encT,    // (B,H,S) projected * K2F
    const float* __restrict__ qry_f,   // (B,T,H) projected * K2F
    const float* __restrict__ v,       // (H)
    const int*   __restrict__ lens,    // (B)
    float* __restrict__ out)           // (B,T,H)
{
    __shared__ float qls[HD * 4];      // [j][t]  8 KB
    __shared__ float pls[8 * 4 * 256]; // [w][t][s] partials 32 KB; aliased as avred[g][t][h]
    __shared__ float wls[SD * 4];      // [s][t] weights 4 KB

    const int blk = blockIdx.x;        // 0..511
    const int b   = blk >> 6;
    const int t0  = (blk & 63) * 4;
    const int tid = threadIdx.x;
    const int w   = tid >> 6;          // wave 0..7
    const int l   = tid & 63;

    {   // stage q transposed: qls[j*4+t] (coalesced per t)
        const float* qf = qry_f + ((size_t)b * TD + t0) * HD;
        #pragma unroll
        for (int t = 0; t < 4; ++t)
            qls[tid * 4 + t] = qf[(size_t)t * HD + tid];
    }
    __syncthreads();

    // ---- scores: wave w covers j in [w*64, w*64+64); lane owns s = 4l..4l+3 ----
    float a[4][4];
    #pragma unroll
    for (int t = 0; t < 4; ++t)
        #pragma unroll
        for (int c = 0; c < 4; ++c) a[t][c] = 0.0f;
    {
        const float* ep = encT + (size_t)b * HD * SD + (size_t)(w * 64) * SD + l * 4;
        const int jbase = w * 64;
        #pragma unroll 2
        for (int jj = 0; jj < 64; ++jj) {
            float4 e = *(const float4*)(ep + (size_t)jj * SD);  // 1 KB/wave, coalesced
            float4 q4 = *(const float4*)&qls[(jbase + jj) * 4]; // uniform -> broadcast
            float vj = v[jbase + jj];                           // uniform -> s_load
            float ev[4] = {e.x, e.y, e.z, e.w};
            float qv[4] = {q4.x, q4.y, q4.z, q4.w};
            #pragma unroll
            for (int t = 0; t < 4; ++t)
                #pragma unroll
                for (int c = 0; c < 4; ++c)
                    a[t][c] = fmaf(vj, RCP(1.0f + EXP2(ev[c] + qv[t])), a[t][c]);
        }
    }
    #pragma unroll
    for (int t = 0; t < 4; ++t)
        *(float4*)&pls[(w * 4 + t) * 256 + l * 4] = make_float4(a[t][0], a[t][1], a[t][2], a[t][3]);
    __syncthreads();

    // ---- combine 8 j-slices + masked softmax: wave t<4 handles t; lane owns 4 s ----
    if (w < 4) {
        const int t = w;
        float p[4] = {0, 0, 0, 0};
        #pragma unroll
        for (int g = 0; g < 8; ++g) {
            float4 pp = *(const float4*)&pls[(g * 4 + t) * 256 + l * 4];
            p[0] += pp.x; p[1] += pp.y; p[2] += pp.z; p[3] += pp.w;
        }
        const int len = lens[b];
        const int s0 = l * 4;
        float sc[4];
        #pragma unroll
        for (int c = 0; c < 4; ++c)
            sc[c] = (s0 + c < len) ? -2.0f * p[c] : -INFINITY;
        float mx = fmaxf(fmaxf(sc[0], sc[1]), fmaxf(sc[2], sc[3]));
        #pragma unroll
        for (int off = 32; off; off >>= 1) mx = fmaxf(mx, __shfl_xor(mx, off));
        float ex[4]; float sum = 0.0f;
        #pragma unroll
        for (int c = 0; c < 4; ++c) { ex[c] = __expf(sc[c] - mx); sum += ex[c]; }
        #pragma unroll
        for (int off = 32; off; off >>= 1) sum += __shfl_xor(sum, off);
        const float inv = RCP(sum);
        #pragma unroll
        for (int c = 0; c < 4; ++c) wls[(s0 + c) * 4 + t] = ex[c] * inv;
    }
    __syncthreads();

    // ---- AV: thread owns (h-float4, s-slice g); accumulates all 4 t ----
    const int g  = tid >> 7;           // s-slice 0..3 (wave-uniform)
    const int h4 = (tid & 127) * 4;
    float* avred = pls;                // safe: pls reads all complete before barrier
    {
        const float* eb = enc + (size_t)b * SD * HD + h4;
        float4 o[4] = {{0,0,0,0},{0,0,0,0},{0,0,0,0},{0,0,0,0}};
        #pragma unroll 2
        for (int ss = 0; ss < 64; ++ss) {
            const int s = g * 64 + ss;
            float4 wv = *(const float4*)&wls[s * 4];   // uniform -> broadcast
            float4 evv = *(const float4*)(eb + (size_t)s * HD);
            float wt[4] = {wv.x, wv.y, wv.z, wv.w};
            #pragma unroll
            for (int t = 0; t < 4; ++t) {
                o[t].x = fmaf(wt[t], evv.x, o[t].x);
                o[t].y = fmaf(wt[t], evv.y, o[t].y);
                o[t].z = fmaf(wt[t], evv.z, o[t].z);
                o[t].w = fmaf(wt[t], evv.w, o[t].w);
            }
        }
        #pragma unroll
        for (int t = 0; t < 4; ++t)
            *(float4*)&avred[(size_t)(g * 4 + t) * 512 + h4] = o[t];
    }
    __syncthreads();

    // final cross-slice reduce + store: thread owns (t = tid>>7, h-float4)
    {
        const int t  = tid >> 7;
        const int hh = (tid & 127) * 4;
        float4 r = {0, 0, 0, 0};
        #pragma unroll
        for (int gg = 0; gg < 4; ++gg) {
            float4 x = *(const float4*)&avred[(size_t)(gg * 4 + t) * 512 + hh];
            r.x += x.x; r.y += x.y; r.z += x.z; r.w += x.w;
        }
        *(float4*)(out + ((size_t)b * TD + t0 + t) * HD + hh) = r;
    }
}

extern "C" void kernel_launch(void* const* d_in, const int* in_sizes, int n_in,
                              void* d_out, int out_size, void* d_ws, size_t ws_size,
                              hipStream_t stream) {
    const float* query = (const float*)d_in[0];
    const float* enc   = (const float*)d_in[1];
    const int*   lens  = (const int*)d_in[2];
    const float* W_h   = (const float*)d_in[3];
    const float* W_s   = (const float*)d_in[4];
    const float* v     = (const float*)d_in[5];
    float* out = (float*)d_out;

    char* ws = (char*)d_ws;
    float* encT = (float*)(ws);                       // 4 MB (B,H,S)
    float* qryf = (float*)(ws + ((size_t)4  << 20));  // 4 MB (B,T,H)
    u16*   Ah   = (u16*)  (ws + ((size_t)8  << 20));  // 4 MB (4096,512)
    u16*   Al   = (u16*)  (ws + ((size_t)12 << 20));  // 4 MB
    u16*   Bh   = (u16*)  (ws + ((size_t)16 << 20));  // 1 MB (1024,512)
    u16*   Bl   = (u16*)  (ws + ((size_t)17 << 20));  // 1 MB

    convert_kernel<<<2560, 256, 0, stream>>>(enc, query, W_h, W_s, Ah, Al, Bh, Bl);

    dim3 pgrid(HD / 64, 64);
    proj_kernel<<<pgrid, 256, 0, stream>>>(Ah, Al, Bh, Bl, encT, qryf);

    attn_kernel<<<BD * (TD / 4), 512, 0, stream>>>(enc, encT, qryf, v, lens, out);
}

// Round 7
// 128.786 us; speedup vs baseline: 1.2959x; 1.1617x over previous
//
#include <hip/hip_runtime.h>
#include <cstddef>
#include <math.h>

#define BD 8
#define TD 256
#define SD 256
#define HD 512
#define K2F 2.885390081777927f    // 2*log2(e): arg of exp2 for e^(2x)

#define EXP2(x) __builtin_amdgcn_exp2f(x)
#define RCP(x)  __builtin_amdgcn_rcpf(x)

typedef __attribute__((ext_vector_type(8))) short short8;
typedef __attribute__((ext_vector_type(4))) float float4v;
typedef unsigned short u16;

__device__ __forceinline__ u16 bf_hi(float x) {
    union { float f; unsigned u; } v; v.f = x;
    unsigned r = v.u + 0x7fff + ((v.u >> 16) & 1);
    return (u16)(r >> 16);
}
__device__ __forceinline__ float bf_tof(u16 h) {
    union { float f; unsigned u; } v; v.u = ((unsigned)h) << 16;
    return v.f;
}
// exp2 with arg clamped so E in [2^-80, 2^80]: products overflow to inf -> rcp -> 0,
// underflow to 0 -> r = 1; no inf*0 NaN path possible.
__device__ __forceinline__ float exp2_sat(float x) {
    return EXP2(fminf(fmaxf(x, -80.0f), 80.0f));
}

// ---------------- convert: fp32 -> split-bf16 planes ----------------
__global__ __launch_bounds__(256) void convert_kernel(
    const float* __restrict__ enc, const float* __restrict__ qry,
    const float* __restrict__ Wh,  const float* __restrict__ Ws,
    u16* __restrict__ Ah, u16* __restrict__ Al,
    u16* __restrict__ Bh, u16* __restrict__ Bl)
{
    const int bid = blockIdx.x, tid = threadIdx.x;
    const float* src; u16 *dh, *dl; size_t i4;
    if (bid < 1024)      { src = enc; dh = Ah;                    dl = Al;                    i4 = (size_t)bid * 256 + tid; }
    else if (bid < 2048) { src = qry; dh = Ah + (size_t)2048*512; dl = Al + (size_t)2048*512; i4 = (size_t)(bid-1024)*256 + tid; }
    else if (bid < 2304) { src = Wh;  dh = Bh;                    dl = Bl;                    i4 = (size_t)(bid-2048)*256 + tid; }
    else                 { src = Ws;  dh = Bh + (size_t)512*512;  dl = Bl + (size_t)512*512;  i4 = (size_t)(bid-2304)*256 + tid; }
    float4 x = ((const float4*)src)[i4];
    u16 h0 = bf_hi(x.x), h1 = bf_hi(x.y), h2 = bf_hi(x.z), h3 = bf_hi(x.w);
    ushort4 hv = make_ushort4(h0, h1, h2, h3);
    ushort4 lv = make_ushort4(bf_hi(x.x - bf_tof(h0)), bf_hi(x.y - bf_tof(h1)),
                              bf_hi(x.z - bf_tof(h2)), bf_hi(x.w - bf_tof(h3)));
    ((ushort4*)dh)[i4] = hv;
    ((ushort4*)dl)[i4] = lv;
}

// ---------------- proj: split-bf16 MFMA GEMM; epilogue stores E = exp2(K2F*proj) ----------------
// Blocks y<32: enc rows -> encT (B,H,S) = E_e.  y>=32: qry rows -> qryf (B,T,H) = E_q.
// 64x64 tile, BK=32 (16 steps), stride-40 LDS, wave owns 32x32 C (2x2 MFMA tiles).
#define LSTR 40
__global__ __launch_bounds__(256) void proj_kernel(
    const u16* __restrict__ Ahg, const u16* __restrict__ Alg,
    const u16* __restrict__ Bhg, const u16* __restrict__ Blg,
    float* __restrict__ encT, float* __restrict__ qryf)
{
    __shared__ u16 LAh[64*LSTR], LAl[64*LSTR], LBh[64*LSTR], LBl[64*LSTR]; // 20 KB

    const int tid = threadIdx.x;
    const int l = tid & 63, w = tid >> 6;
    const int rf = l & 15, q = l >> 4;
    const int my = blockIdx.y;
    const bool isq = my >= 32;
    const int m0 = my * 64;                 // row in stacked A (0..4095)
    const int n0 = blockIdx.x * 64;
    const int brow0 = (isq ? 512 : 0) + n0; // row in stacked B

    const int srow = tid >> 2;              // staging row 0..63
    const int scol = (tid & 3) * 8;         // staging col 0,8,16,24
    const u16* pAh = Ahg + (size_t)(m0 + srow) * HD + scol;
    const u16* pAl = Alg + (size_t)(m0 + srow) * HD + scol;
    const u16* pBh = Bhg + (size_t)(brow0 + srow) * HD + scol;
    const u16* pBl = Blg + (size_t)(brow0 + srow) * HD + scol;

    const int mi = (w & 1) * 32, ni = (w >> 1) * 32;

    float4v acc[2][2] = {{{0,0,0,0},{0,0,0,0}},{{0,0,0,0},{0,0,0,0}}};

    short8 rah = *(const short8*)pAh;
    short8 ral = *(const short8*)pAl;
    short8 rbh = *(const short8*)pBh;
    short8 rbl = *(const short8*)pBl;

    for (int ks = 0; ks < 16; ++ks) {
        if (ks) __syncthreads();
        *(short8*)&LAh[srow * LSTR + scol] = rah;
        *(short8*)&LAl[srow * LSTR + scol] = ral;
        *(short8*)&LBh[srow * LSTR + scol] = rbh;
        *(short8*)&LBl[srow * LSTR + scol] = rbl;
        __syncthreads();
        if (ks + 1 < 16) {
            const int ko = (ks + 1) * 32;
            rah = *(const short8*)(pAh + ko);
            ral = *(const short8*)(pAl + ko);
            rbh = *(const short8*)(pBh + ko);
            rbl = *(const short8*)(pBl + ko);
        }
        short8 ah[2], al[2], bh[2], bl[2];
        #pragma unroll
        for (int i = 0; i < 2; ++i) {
            ah[i] = *(const short8*)&LAh[(mi + i * 16 + rf) * LSTR + q * 8];
            al[i] = *(const short8*)&LAl[(mi + i * 16 + rf) * LSTR + q * 8];
            bh[i] = *(const short8*)&LBh[(ni + i * 16 + rf) * LSTR + q * 8];
            bl[i] = *(const short8*)&LBl[(ni + i * 16 + rf) * LSTR + q * 8];
        }
        #pragma unroll
        for (int i = 0; i < 2; ++i)
            #pragma unroll
            for (int j = 0; j < 2; ++j) {
                acc[i][j] = __builtin_amdgcn_mfma_f32_16x16x32_bf16(ah[i], bh[j], acc[i][j], 0, 0, 0);
                acc[i][j] = __builtin_amdgcn_mfma_f32_16x16x32_bf16(ah[i], bl[j], acc[i][j], 0, 0, 0);
                acc[i][j] = __builtin_amdgcn_mfma_f32_16x16x32_bf16(al[i], bh[j], acc[i][j], 0, 0, 0);
            }
    }

    // Epilogue: m-local = mi + i*16 + q*4 + r, n-local = ni + j*16 + rf (R4-verified)
    // Stores E = exp2_sat(K2F * proj) — the attn kernel consumes exponentials directly.
    if (!isq) {
        const int b  = m0 >> 8;
        const int sb = (m0 & 255) + mi + q * 4;
        float* base = encT + (size_t)b * HD * SD;
        #pragma unroll
        for (int i = 0; i < 2; ++i)
            #pragma unroll
            for (int j = 0; j < 2; ++j) {
                float4 o = make_float4(exp2_sat(acc[i][j][0]*K2F), exp2_sat(acc[i][j][1]*K2F),
                                       exp2_sat(acc[i][j][2]*K2F), exp2_sat(acc[i][j][3]*K2F));
                *(float4*)(base + (size_t)(n0 + ni + j * 16 + rf) * SD + sb + i * 16) = o;
            }
    } else {
        const int mrow = (m0 - 2048) + mi + q * 4;
        #pragma unroll
        for (int i = 0; i < 2; ++i)
            #pragma unroll
            for (int j = 0; j < 2; ++j)
                #pragma unroll
                for (int r = 0; r < 4; ++r)
                    qryf[(size_t)(mrow + i * 16 + r) * HD + n0 + ni + j * 16 + rf] =
                        exp2_sat(acc[i][j][r] * K2F);
    }
}

// ---------------- attn: r = 1/(1 + E_e*E_q) — 2 VALU + 1 trans per element ----------------
// score'_s(t) = -2 * sum_j v_j * r
__global__ __launch_bounds__(512) void attn_kernel(
    const float* __restrict__ enc,     // (B,S,H) raw
    const float* __restrict__ encT,    // (B,H,S) E_e
    const float* __restrict__ qry_f,   // (B,T,H) E_q
    const float* __restrict__ v,       // (H)
    const int*   __restrict__ lens,    // (B)
    float* __restrict__ out)           // (B,T,H)
{
    __shared__ float qls[HD * 4];      // [j][t]  8 KB (E_q)
    __shared__ float pls[8 * 4 * 256]; // [w][t][s] partials 32 KB; aliased as avred[g][t][h]
    __shared__ float wls[4 * SD];      // [t][s] weights 4 KB

    const int blk = blockIdx.x;        // 0..511
    const int b   = blk >> 6;
    const int t0  = (blk & 63) * 4;
    const int tid = threadIdx.x;
    const int w   = tid >> 6;          // wave 0..7
    const int l   = tid & 63;

    {   // stage E_q transposed: qls[j*4+t], single b128 store (conflict-free)
        const float* qf = qry_f + ((size_t)b * TD + t0) * HD;
        float4 qv;
        qv.x = qf[0 * HD + tid]; qv.y = qf[1 * HD + tid];
        qv.z = qf[2 * HD + tid]; qv.w = qf[3 * HD + tid];
        *(float4*)&qls[tid * 4] = qv;
    }
    __syncthreads();

    // ---- scores: wave w covers j in [w*64, w*64+64); lane owns s = 4l..4l+3 ----
    float a[4][4];
    #pragma unroll
    for (int t = 0; t < 4; ++t)
        #pragma unroll
        for (int c = 0; c < 4; ++c) a[t][c] = 0.0f;
    {
        const float* ep = encT + (size_t)b * HD * SD + (size_t)(w * 64) * SD + l * 4;
        const int jbase = w * 64;
        #pragma unroll 4
        for (int jj = 0; jj < 64; ++jj) {
            float4 e = *(const float4*)(ep + (size_t)jj * SD);  // E_e, coalesced
            float4 q4 = *(const float4*)&qls[(jbase + jj) * 4]; // E_q, broadcast
            float vj = v[jbase + jj];                           // uniform -> s_load
            float ev[4] = {e.x, e.y, e.z, e.w};
            float qv[4] = {q4.x, q4.y, q4.z, q4.w};
            #pragma unroll
            for (int t = 0; t < 4; ++t)
                #pragma unroll
                for (int c = 0; c < 4; ++c) {
                    float p = fmaf(ev[c], qv[t], 1.0f);
                    a[t][c] = fmaf(vj, RCP(p), a[t][c]);
                }
        }
    }
    #pragma unroll
    for (int t = 0; t < 4; ++t)
        *(float4*)&pls[(w * 4 + t) * 256 + l * 4] = make_float4(a[t][0], a[t][1], a[t][2], a[t][3]);
    __syncthreads();

    // ---- combine 8 j-slices + masked softmax: wave t<4 handles t; lane owns 4 s ----
    if (w < 4) {
        const int t = w;
        float p[4] = {0, 0, 0, 0};
        #pragma unroll
        for (int g = 0; g < 8; ++g) {
            float4 pp = *(const float4*)&pls[(g * 4 + t) * 256 + l * 4];
            p[0] += pp.x; p[1] += pp.y; p[2] += pp.z; p[3] += pp.w;
        }
        const int len = lens[b];
        const int s0 = l * 4;
        float sc[4];
        #pragma unroll
        for (int c = 0; c < 4; ++c)
            sc[c] = (s0 + c < len) ? -2.0f * p[c] : -INFINITY;
        float mx = fmaxf(fmaxf(sc[0], sc[1]), fmaxf(sc[2], sc[3]));
        #pragma unroll
        for (int off = 32; off; off >>= 1) mx = fmaxf(mx, __shfl_xor(mx, off));
        float ex[4]; float sum = 0.0f;
        #pragma unroll
        for (int c = 0; c < 4; ++c) { ex[c] = __expf(sc[c] - mx); sum += ex[c]; }
        #pragma unroll
        for (int off = 32; off; off >>= 1) sum += __shfl_xor(sum, off);
        const float inv = RCP(sum);
        *(float4*)&wls[t * SD + s0] = make_float4(ex[0]*inv, ex[1]*inv, ex[2]*inv, ex[3]*inv);
    }
    __syncthreads();

    // ---- AV: thread owns (h-float4, s-slice g); accumulates all 4 t ----
    const int g  = tid >> 7;           // s-slice 0..3 (wave-uniform)
    const int h4 = (tid & 127) * 4;
    float* avred = pls;                // safe: pls reads complete before barrier
    {
        const float* eb = enc + (size_t)b * SD * HD + h4;
        float4 o[4] = {{0,0,0,0},{0,0,0,0},{0,0,0,0},{0,0,0,0}};
        #pragma unroll 2
        for (int ss = 0; ss < 64; ++ss) {
            const int s = g * 64 + ss;
            float4 evv = *(const float4*)(eb + (size_t)s * HD);
            float wt[4];
            #pragma unroll
            for (int t = 0; t < 4; ++t) wt[t] = wls[t * SD + s];   // broadcast
            #pragma unroll
            for (int t = 0; t < 4; ++t) {
                o[t].x = fmaf(wt[t], evv.x, o[t].x);
                o[t].y = fmaf(wt[t], evv.y, o[t].y);
                o[t].z = fmaf(wt[t], evv.z, o[t].z);
                o[t].w = fmaf(wt[t], evv.w, o[t].w);
            }
        }
        #pragma unroll
        for (int t = 0; t < 4; ++t)
            *(float4*)&avred[(size_t)(g * 4 + t) * 512 + h4] = o[t];
    }
    __syncthreads();

    // final cross-slice reduce + store: thread owns (t = tid>>7, h-float4)
    {
        const int t  = tid >> 7;
        const int hh = (tid & 127) * 4;
        float4 r = {0, 0, 0, 0};
        #pragma unroll
        for (int gg = 0; gg < 4; ++gg) {
            float4 x = *(const float4*)&avred[(size_t)(gg * 4 + t) * 512 + hh];
            r.x += x.x; r.y += x.y; r.z += x.z; r.w += x.w;
        }
        *(float4*)(out + ((size_t)b * TD + t0 + t) * HD + hh) = r;
    }
}

extern "C" void kernel_launch(void* const* d_in, const int* in_sizes, int n_in,
                              void* d_out, int out_size, void* d_ws, size_t ws_size,
                              hipStream_t stream) {
    const float* query = (const float*)d_in[0];
    const float* enc   = (const float*)d_in[1];
    const int*   lens  = (const int*)d_in[2];
    const float* W_h   = (const float*)d_in[3];
    const float* W_s   = (const float*)d_in[4];
    const float* v     = (const float*)d_in[5];
    float* out = (float*)d_out;

    char* ws = (char*)d_ws;
    float* encT = (float*)(ws);                       // 4 MB (B,H,S)  E_e
    float* qryf = (float*)(ws + ((size_t)4  << 20));  // 4 MB (B,T,H)  E_q
    u16*   Ah   = (u16*)  (ws + ((size_t)8  << 20));  // 4 MB (4096,512)
    u16*   Al   = (u16*)  (ws + ((size_t)12 << 20));  // 4 MB
    u16*   Bh   = (u16*)  (ws + ((size_t)16 << 20));  // 1 MB (1024,512)
    u16*   Bl   = (u16*)  (ws + ((size_t)17 << 20));  // 1 MB

    convert_kernel<<<2560, 256, 0, stream>>>(enc, query, W_h, W_s, Ah, Al, Bh, Bl);

    dim3 pgrid(HD / 64, 64);
    proj_kernel<<<pgrid, 256, 0, stream>>>(Ah, Al, Bh, Bl, encT, qryf);

    attn_kernel<<<BD * (TD / 4), 512, 0, stream>>>(enc, encT, qryf, v, lens, out);
}

// Round 8
// 124.506 us; speedup vs baseline: 1.3404x; 1.0344x over previous
//
#include <hip/hip_runtime.h>
#include <cstddef>
#include <math.h>

#define BD 8
#define TD 256
#define SD 256
#define HD 512
#define K2F 2.885390081777927f    // 2*log2(e): arg of exp2 for e^(2x)

#define EXP2(x) __builtin_amdgcn_exp2f(x)
#define RCP(x)  __builtin_amdgcn_rcpf(x)

typedef __attribute__((ext_vector_type(8))) _Float16 half8;
typedef __attribute__((ext_vector_type(4))) float float4v;

// exp2 with arg clamped so E in [2^-80, 2^80]: products overflow to inf -> rcp -> 0,
// underflow to 0 -> r = 1; no inf*0 NaN path possible.
__device__ __forceinline__ float exp2_sat(float x) {
    return EXP2(fminf(fmaxf(x, -80.0f), 80.0f));
}

// ---------------- proj: fp16 MFMA GEMM, fused fp32->fp16 convert in staging ----------------
// Blocks y<32: enc @ W_h^T -> encT (B,H,S) = E_e (exp2 of K2F*proj, transposed).
// Blocks y>=32: qry @ W_s^T -> qryf (B,T,H) = E_q.
// 64x64 tile, BK=32 (16 steps), stride-40 LDS, wave owns 32x32 C (2x2 MFMA tiles, f16 K=32).
#define LSTR 40
__global__ __launch_bounds__(256) void proj_kernel(
    const float* __restrict__ enc, const float* __restrict__ qry,
    const float* __restrict__ Wh,  const float* __restrict__ Ws,
    float* __restrict__ encT, float* __restrict__ qryf)
{
    __shared__ _Float16 LA[64 * LSTR], LB[64 * LSTR];   // 5 KB each

    const int tid = threadIdx.x;
    const int l = tid & 63, w = tid >> 6;
    const int rf = l & 15, q = l >> 4;
    const int my = blockIdx.y;
    const bool isq = my >= 32;
    const int m0 = my * 64;                 // row in stacked A space (0..4095)
    const int n0 = blockIdx.x * 64;

    const int srow = tid >> 2;              // staging row 0..63
    const int scol = (tid & 3) * 8;         // staging col 0,8,16,24 (floats)
    const float* Abase = isq
        ? qry + (size_t)(m0 - 2048 + srow) * HD + scol
        : enc + (size_t)(m0 + srow) * HD + scol;
    const float* Bbase = (isq ? Ws : Wh) + (size_t)(n0 + srow) * HD + scol;

    const int mi = (w & 1) * 32, ni = (w >> 1) * 32;

    float4v acc[2][2] = {{{0,0,0,0},{0,0,0,0}},{{0,0,0,0},{0,0,0,0}}};

    float4 a0 = *(const float4*)(Abase);
    float4 a1 = *(const float4*)(Abase + 4);
    float4 b0 = *(const float4*)(Bbase);
    float4 b1 = *(const float4*)(Bbase + 4);

    for (int ks = 0; ks < 16; ++ks) {
        if (ks) __syncthreads();
        {   // convert + stage (fp16 RNE via v_cvt_f16_f32)
            float af[8] = {a0.x,a0.y,a0.z,a0.w,a1.x,a1.y,a1.z,a1.w};
            float bf[8] = {b0.x,b0.y,b0.z,b0.w,b1.x,b1.y,b1.z,b1.w};
            half8 ha, hb;
            #pragma unroll
            for (int i = 0; i < 8; ++i) { ha[i] = (_Float16)af[i]; hb[i] = (_Float16)bf[i]; }
            *(half8*)&LA[srow * LSTR + scol] = ha;
            *(half8*)&LB[srow * LSTR + scol] = hb;
        }
        __syncthreads();
        if (ks + 1 < 16) {
            const int ko = (ks + 1) * 32;
            a0 = *(const float4*)(Abase + ko);
            a1 = *(const float4*)(Abase + ko + 4);
            b0 = *(const float4*)(Bbase + ko);
            b1 = *(const float4*)(Bbase + ko + 4);
        }
        half8 ah[2], bh[2];
        #pragma unroll
        for (int i = 0; i < 2; ++i) {
            ah[i] = *(const half8*)&LA[(mi + i * 16 + rf) * LSTR + q * 8];
            bh[i] = *(const half8*)&LB[(ni + i * 16 + rf) * LSTR + q * 8];
        }
        #pragma unroll
        for (int i = 0; i < 2; ++i)
            #pragma unroll
            for (int j = 0; j < 2; ++j)
                acc[i][j] = __builtin_amdgcn_mfma_f32_16x16x32_f16(ah[i], bh[j], acc[i][j], 0, 0, 0);
    }

    // Epilogue (R4-verified C map: m-local = mi + i*16 + q*4 + r, n-local = ni + j*16 + rf)
    // Stores E = exp2_sat(K2F * proj).
    if (!isq) {
        const int b  = m0 >> 8;
        const int sb = (m0 & 255) + mi + q * 4;
        float* base = encT + (size_t)b * HD * SD;
        #pragma unroll
        for (int i = 0; i < 2; ++i)
            #pragma unroll
            for (int j = 0; j < 2; ++j) {
                float4 o = make_float4(exp2_sat(acc[i][j][0]*K2F), exp2_sat(acc[i][j][1]*K2F),
                                       exp2_sat(acc[i][j][2]*K2F), exp2_sat(acc[i][j][3]*K2F));
                *(float4*)(base + (size_t)(n0 + ni + j * 16 + rf) * SD + sb + i * 16) = o;
            }
    } else {
        const int mrow = (m0 - 2048) + mi + q * 4;
        #pragma unroll
        for (int i = 0; i < 2; ++i)
            #pragma unroll
            for (int j = 0; j < 2; ++j)
                #pragma unroll
                for (int r = 0; r < 4; ++r)
                    qryf[(size_t)(mrow + i * 16 + r) * HD + n0 + ni + j * 16 + rf] =
                        exp2_sat(acc[i][j][r] * K2F);
    }
}

// ---------------- attn: r = 1/(1 + E_e*E_q); wave owns j-slice, all 4 t per e-load ----------------
__global__ __launch_bounds__(512) void attn_kernel(
    const float* __restrict__ enc,     // (B,S,H) raw
    const float* __restrict__ encT,    // (B,H,S) E_e
    const float* __restrict__ qry_f,   // (B,T,H) E_q
    const float* __restrict__ v,       // (H)
    const int*   __restrict__ lens,    // (B)
    float* __restrict__ out)           // (B,T,H)
{
    __shared__ float qls[HD * 4];      // [j][t]  8 KB (E_q)
    __shared__ float pls[8 * 4 * 256]; // [w][t][s] partials 32 KB; aliased as avred[g][t][h]
    __shared__ float wls[4 * SD];      // [t][s] weights 4 KB

    const int blk = blockIdx.x;        // 0..511
    const int b   = blk >> 6;
    const int t0  = (blk & 63) * 4;
    const int tid = threadIdx.x;
    const int w   = tid >> 6;          // wave 0..7
    const int l   = tid & 63;

    {   // stage E_q transposed: qls[j*4+t], single b128 store
        const float* qf = qry_f + ((size_t)b * TD + t0) * HD;
        float4 qv;
        qv.x = qf[0 * HD + tid]; qv.y = qf[1 * HD + tid];
        qv.z = qf[2 * HD + tid]; qv.w = qf[3 * HD + tid];
        *(float4*)&qls[tid * 4] = qv;
    }
    __syncthreads();

    // ---- scores: wave w covers j in [w*64, w*64+64); lane owns s = 4l..4l+3 ----
    float a[4][4];
    #pragma unroll
    for (int t = 0; t < 4; ++t)
        #pragma unroll
        for (int c = 0; c < 4; ++c) a[t][c] = 0.0f;
    {
        const float* ep = encT + (size_t)b * HD * SD + (size_t)(w * 64) * SD + l * 4;
        const int jbase = w * 64;
        float4 e = *(const float4*)ep;          // prefetch j=0
        #pragma unroll 2
        for (int jj = 0; jj < 64; ++jj) {
            // prefetch next row (unconditional; last read lands in ws, harmless)
            float4 en = *(const float4*)(ep + (size_t)(jj + 1) * SD);
            float4 q4 = *(const float4*)&qls[(jbase + jj) * 4]; // E_q, broadcast
            float vj = v[jbase + jj];                           // uniform -> s_load
            float ev[4] = {e.x, e.y, e.z, e.w};
            float qv[4] = {q4.x, q4.y, q4.z, q4.w};
            #pragma unroll
            for (int t = 0; t < 4; ++t)
                #pragma unroll
                for (int c = 0; c < 4; ++c) {
                    float p = fmaf(ev[c], qv[t], 1.0f);
                    a[t][c] = fmaf(vj, RCP(p), a[t][c]);
                }
            e = en;
        }
    }
    #pragma unroll
    for (int t = 0; t < 4; ++t)
        *(float4*)&pls[(w * 4 + t) * 256 + l * 4] = make_float4(a[t][0], a[t][1], a[t][2], a[t][3]);
    __syncthreads();

    // ---- combine 8 j-slices + masked softmax: wave t<4 handles t; lane owns 4 s ----
    if (w < 4) {
        const int t = w;
        float p[4] = {0, 0, 0, 0};
        #pragma unroll
        for (int g = 0; g < 8; ++g) {
            float4 pp = *(const float4*)&pls[(g * 4 + t) * 256 + l * 4];
            p[0] += pp.x; p[1] += pp.y; p[2] += pp.z; p[3] += pp.w;
        }
        const int len = lens[b];
        const int s0 = l * 4;
        float sc[4];
        #pragma unroll
        for (int c = 0; c < 4; ++c)
            sc[c] = (s0 + c < len) ? -2.0f * p[c] : -INFINITY;
        float mx = fmaxf(fmaxf(sc[0], sc[1]), fmaxf(sc[2], sc[3]));
        #pragma unroll
        for (int off = 32; off; off >>= 1) mx = fmaxf(mx, __shfl_xor(mx, off));
        float ex[4]; float sum = 0.0f;
        #pragma unroll
        for (int c = 0; c < 4; ++c) { ex[c] = __expf(sc[c] - mx); sum += ex[c]; }
        #pragma unroll
        for (int off = 32; off; off >>= 1) sum += __shfl_xor(sum, off);
        const float inv = RCP(sum);
        *(float4*)&wls[t * SD + s0] = make_float4(ex[0]*inv, ex[1]*inv, ex[2]*inv, ex[3]*inv);
    }
    __syncthreads();

    // ---- AV: thread owns (h-float4, s-slice g); accumulates all 4 t ----
    const int g  = tid >> 7;           // s-slice 0..3 (wave-uniform)
    const int h4 = (tid & 127) * 4;
    float* avred = pls;                // safe: pls reads complete before barrier
    {
        const float* eb = enc + (size_t)b * SD * HD + h4;
        float4 o[4] = {{0,0,0,0},{0,0,0,0},{0,0,0,0},{0,0,0,0}};
        #pragma unroll 2
        for (int ss = 0; ss < 64; ++ss) {
            const int s = g * 64 + ss;
            float4 evv = *(const float4*)(eb + (size_t)s * HD);
            float wt[4];
            #pragma unroll
            for (int t = 0; t < 4; ++t) wt[t] = wls[t * SD + s];   // broadcast
            #pragma unroll
            for (int t = 0; t < 4; ++t) {
                o[t].x = fmaf(wt[t], evv.x, o[t].x);
                o[t].y = fmaf(wt[t], evv.y, o[t].y);
                o[t].z = fmaf(wt[t], evv.z, o[t].z);
                o[t].w = fmaf(wt[t], evv.w, o[t].w);
            }
        }
        #pragma unroll
        for (int t = 0; t < 4; ++t)
            *(float4*)&avred[(size_t)(g * 4 + t) * 512 + h4] = o[t];
    }
    __syncthreads();

    // final cross-slice reduce + store: thread owns (t = tid>>7, h-float4)
    {
        const int t  = tid >> 7;
        const int hh = (tid & 127) * 4;
        float4 r = {0, 0, 0, 0};
        #pragma unroll
        for (int gg = 0; gg < 4; ++gg) {
            float4 x = *(const float4*)&avred[(size_t)(gg * 4 + t) * 512 + hh];
            r.x += x.x; r.y += x.y; r.z += x.z; r.w += x.w;
        }
        *(float4*)(out + ((size_t)b * TD + t0 + t) * HD + hh) = r;
    }
}

extern "C" void kernel_launch(void* const* d_in, const int* in_sizes, int n_in,
                              void* d_out, int out_size, void* d_ws, size_t ws_size,
                              hipStream_t stream) {
    const float* query = (const float*)d_in[0];
    const float* enc   = (const float*)d_in[1];
    const int*   lens  = (const int*)d_in[2];
    const float* W_h   = (const float*)d_in[3];
    const float* W_s   = (const float*)d_in[4];
    const float* v     = (const float*)d_in[5];
    float* out = (float*)d_out;

    char* ws = (char*)d_ws;
    float* encT = (float*)(ws);                       // 4 MB (B,H,S)  E_e
    float* qryf = (float*)(ws + ((size_t)4 << 20));   // 4 MB (B,T,H)  E_q

    dim3 pgrid(HD / 64, 64);           // 32 enc m-tiles + 32 qry m-tiles
    proj_kernel<<<pgrid, 256, 0, stream>>>(enc, query, W_h, W_s, encT, qryf);

    attn_kernel<<<BD * (TD / 4), 512, 0, stream>>>(enc, encT, qryf, v, lens, out);
}

// Round 10
// 120.904 us; speedup vs baseline: 1.3804x; 1.0298x over previous
//
#include <hip/hip_runtime.h>
#include <hip/hip_cooperative_groups.h>
#include <cstddef>
#include <math.h>

namespace cg = cooperative_groups;

#define BD 8
#define TD 256
#define SD 256
#define HD 512
#define K2F 2.885390081777927f    // 2*log2(e): arg of exp2 for e^(2x)

#define EXP2(x) __builtin_amdgcn_exp2f(x)
#define RCP(x)  __builtin_amdgcn_rcpf(x)

typedef __attribute__((ext_vector_type(8))) _Float16 half8;
typedef __attribute__((ext_vector_type(4))) _Float16 half4;
typedef __attribute__((ext_vector_type(4))) float float4v;

// exp2 with arg clamped so E in [2^-80, 2^80]: products overflow to inf -> rcp -> 0,
// underflow to 0 -> r = 1; no inf*0 NaN path possible.
__device__ __forceinline__ float exp2_sat(float x) {
    return EXP2(fminf(fmaxf(x, -80.0f), 80.0f));
}

#define LSTR 40   // LDS row stride (halves) for proj staging

// ============ fused cooperative kernel: proj -> grid.sync -> attn. 28 KB LDS ============
__global__ __launch_bounds__(512) void fused_kernel(
    const float* __restrict__ enc,   // (B,S,H)
    const float* __restrict__ qry,   // (B,T,H)
    const float* __restrict__ Wh,    // (H,H)
    const float* __restrict__ Ws,    // (H,H)
    const float* __restrict__ v,     // (H)
    const int*   __restrict__ lens,  // (B)
    float* __restrict__ encT,        // ws: (B,H,S) E_e
    float* __restrict__ qryf,        // ws: (B,T,H) E_q
    float* __restrict__ out)         // (B,T,H)
{
    __shared__ float smem[7168];     // 28 KB: qls[2048] | pls[4096] | wls[1024]

    const int bid = blockIdx.x;      // 0..511
    const int tid = threadIdx.x;     // 0..511
    const int l   = tid & 63;
    const int w   = tid >> 6;        // wave 0..7
    const int rf  = l & 15;
    const int q   = l >> 4;

    // ================= PHASE A: proj (fp16 MFMA, fused convert), 10 KB LDS =================
    {
        _Float16* LA = (_Float16*)smem;            // 64*40 halves = 5120 B
        _Float16* LB = (_Float16*)(smem + 1280);

        const int my = bid >> 3;
        const bool isq = my >= 32;
        const int m0 = my * 64;                    // stacked row 0..4095
        const int n0 = (bid & 7) * 64;

        const int srow = tid >> 3;                 // staging row 0..63
        const int scol = (tid & 7) * 4;            // staging col (floats)
        const float* Abase = isq
            ? qry + (size_t)(m0 - 2048 + srow) * HD + scol
            : enc + (size_t)(m0 + srow) * HD + scol;
        const float* Bbase = (isq ? Ws : Wh) + (size_t)(n0 + srow) * HD + scol;

        const int mi = (w & 3) * 16;               // wave row-strip
        const int ni = (w >> 2) * 32;              // wave col-strip (2 MFMA tiles)

        float4v acc[2] = {{0,0,0,0},{0,0,0,0}};

        float4 a0 = *(const float4*)(Abase);
        float4 b0 = *(const float4*)(Bbase);

        for (int ks = 0; ks < 16; ++ks) {
            if (ks) __syncthreads();
            {
                half4 ha, hb;
                ha[0]=(_Float16)a0.x; ha[1]=(_Float16)a0.y; ha[2]=(_Float16)a0.z; ha[3]=(_Float16)a0.w;
                hb[0]=(_Float16)b0.x; hb[1]=(_Float16)b0.y; hb[2]=(_Float16)b0.z; hb[3]=(_Float16)b0.w;
                *(half4*)&LA[srow * LSTR + scol] = ha;
                *(half4*)&LB[srow * LSTR + scol] = hb;
            }
            __syncthreads();
            if (ks + 1 < 16) {
                const int ko = (ks + 1) * 32;
                a0 = *(const float4*)(Abase + ko);
                b0 = *(const float4*)(Bbase + ko);
            }
            half8 ah = *(const half8*)&LA[(mi + rf) * LSTR + q * 8];
            #pragma unroll
            for (int j = 0; j < 2; ++j) {
                half8 bh = *(const half8*)&LB[(ni + j * 16 + rf) * LSTR + q * 8];
                acc[j] = __builtin_amdgcn_mfma_f32_16x16x32_f16(ah, bh, acc[j], 0, 0, 0);
            }
        }

        // Epilogue (verified map: m-local = mi + q*4 + r, n-local = ni + j*16 + rf).
        if (!isq) {
            const int b  = m0 >> 8;
            const int sb = (m0 & 255) + mi + q * 4;
            float* base = encT + (size_t)b * HD * SD;
            #pragma unroll
            for (int j = 0; j < 2; ++j) {
                float4 o = make_float4(exp2_sat(acc[j][0]*K2F), exp2_sat(acc[j][1]*K2F),
                                       exp2_sat(acc[j][2]*K2F), exp2_sat(acc[j][3]*K2F));
                *(float4*)(base + (size_t)(n0 + ni + j * 16 + rf) * SD + sb) = o;
            }
        } else {
            const int mrow = (m0 - 2048) + mi + q * 4;
            #pragma unroll
            for (int j = 0; j < 2; ++j)
                #pragma unroll
                for (int r = 0; r < 4; ++r)
                    qryf[(size_t)(mrow + r) * HD + n0 + ni + j * 16 + rf] =
                        exp2_sat(acc[j][r] * K2F);
        }
    }

    cg::this_grid().sync();   // device-scope: encT/qryf visible to all blocks

    // ================= PHASE B: attn, 28 KB LDS =================
    {
        float* qls = smem;            // [j][t] 2048 floats
        float* pls = smem + 2048;     // [slice(4)][t(4)][s(256)] 4096 floats; aliased avred
        float* wls = smem + 6144;     // [t][s] 1024 floats

        const int b  = bid >> 6;
        const int t0 = (bid & 63) * 4;

        {   // stage E_q transposed: qls[j*4+t]
            const float* qf = qryf + ((size_t)b * TD + t0) * HD;
            float4 qv;
            qv.x = qf[0 * HD + tid]; qv.y = qf[1 * HD + tid];
            qv.z = qf[2 * HD + tid]; qv.w = qf[3 * HD + tid];
            *(float4*)&qls[tid * 4] = qv;
        }
        __syncthreads();

        // ---- scores: wave w covers j-slice w; lane owns s = 4l..4l+3 ----
        float a[4][4];
        #pragma unroll
        for (int t = 0; t < 4; ++t)
            #pragma unroll
            for (int c = 0; c < 4; ++c) a[t][c] = 0.0f;
        {
            const float* ep = encT + (size_t)b * HD * SD + (size_t)(w * 64) * SD + l * 4;
            const int jbase = w * 64;
            #pragma unroll 4
            for (int jj = 0; jj < 64; ++jj) {
                float4 e = *(const float4*)(ep + (size_t)jj * SD);  // E_e, coalesced
                float4 q4 = *(const float4*)&qls[(jbase + jj) * 4]; // E_q, broadcast
                float vj = v[jbase + jj];                           // uniform -> s_load
                float ev[4] = {e.x, e.y, e.z, e.w};
                float qv[4] = {q4.x, q4.y, q4.z, q4.w};
                #pragma unroll
                for (int t = 0; t < 4; ++t)
                    #pragma unroll
                    for (int c = 0; c < 4; ++c) {
                        float p = fmaf(ev[c], qv[t], 1.0f);
                        a[t][c] = fmaf(vj, RCP(p), a[t][c]);
                    }
            }
        }
        // two-stage partial accumulate (keeps pls at 16 KB)
        if (w < 4) {
            #pragma unroll
            for (int t = 0; t < 4; ++t)
                *(float4*)&pls[(w * 4 + t) * 256 + l * 4] =
                    make_float4(a[t][0], a[t][1], a[t][2], a[t][3]);
        }
        __syncthreads();
        if (w >= 4) {
            #pragma unroll
            for (int t = 0; t < 4; ++t) {
                float4 c4 = *(const float4*)&pls[((w - 4) * 4 + t) * 256 + l * 4];
                c4.x += a[t][0]; c4.y += a[t][1]; c4.z += a[t][2]; c4.w += a[t][3];
                *(float4*)&pls[((w - 4) * 4 + t) * 256 + l * 4] = c4;
            }
        }
        __syncthreads();

        // ---- combine 4 slices + masked softmax: wave t<4 handles t; lane owns 4 s ----
        if (w < 4) {
            const int t = w;
            float p[4] = {0, 0, 0, 0};
            #pragma unroll
            for (int g = 0; g < 4; ++g) {
                float4 pp = *(const float4*)&pls[(g * 4 + t) * 256 + l * 4];
                p[0] += pp.x; p[1] += pp.y; p[2] += pp.z; p[3] += pp.w;
            }
            const int len = lens[b];
            const int s0 = l * 4;
            float sc[4];
            #pragma unroll
            for (int c = 0; c < 4; ++c)
                sc[c] = (s0 + c < len) ? -2.0f * p[c] : -INFINITY;
            float mx = fmaxf(fmaxf(sc[0], sc[1]), fmaxf(sc[2], sc[3]));
            #pragma unroll
            for (int off = 32; off; off >>= 1) mx = fmaxf(mx, __shfl_xor(mx, off));
            float ex[4]; float sum = 0.0f;
            #pragma unroll
            for (int c = 0; c < 4; ++c) { ex[c] = __expf(sc[c] - mx); sum += ex[c]; }
            #pragma unroll
            for (int off = 32; off; off >>= 1) sum += __shfl_xor(sum, off);
            const float inv = RCP(sum);
            *(float4*)&wls[t * SD + s0] = make_float4(ex[0]*inv, ex[1]*inv, ex[2]*inv, ex[3]*inv);
        }
        __syncthreads();

        // ---- AV: thread owns (h-float4, s-slice sg of 64); accumulates all 4 t ----
        const int sg = tid >> 7;          // 0..3 (wave-uniform)
        const int h4 = (tid & 127) * 4;
        float* avred = pls;               // [slice(2)][t(4)][h(512)] = 4096 floats
        float4 o[4] = {{0,0,0,0},{0,0,0,0},{0,0,0,0},{0,0,0,0}};
        {
            const float* eb = enc + (size_t)b * SD * HD + h4;
            #pragma unroll 2
            for (int ss = 0; ss < 64; ++ss) {
                const int s = sg * 64 + ss;
                float4 evv = *(const float4*)(eb + (size_t)s * HD);
                float wt[4];
                #pragma unroll
                for (int t = 0; t < 4; ++t) wt[t] = wls[t * SD + s];
                #pragma unroll
                for (int t = 0; t < 4; ++t) {
                    o[t].x = fmaf(wt[t], evv.x, o[t].x);
                    o[t].y = fmaf(wt[t], evv.y, o[t].y);
                    o[t].z = fmaf(wt[t], evv.z, o[t].z);
                    o[t].w = fmaf(wt[t], evv.w, o[t].w);
                }
            }
        }
        if (sg < 2) {
            #pragma unroll
            for (int t = 0; t < 4; ++t)
                *(float4*)&avred[(size_t)(sg * 4 + t) * 512 + h4] = o[t];
        }
        __syncthreads();
        if (sg >= 2) {
            #pragma unroll
            for (int t = 0; t < 4; ++t) {
                float4 c4 = *(const float4*)&avred[(size_t)((sg - 2) * 4 + t) * 512 + h4];
                c4.x += o[t].x; c4.y += o[t].y; c4.z += o[t].z; c4.w += o[t].w;
                *(float4*)&avred[(size_t)((sg - 2) * 4 + t) * 512 + h4] = c4;
            }
        }
        __syncthreads();

        // final reduce + store: thread owns (t = tid>>7, h-float4)
        {
            const int t  = tid >> 7;
            const int hh = (tid & 127) * 4;
            float4 x0 = *(const float4*)&avred[(size_t)(0 * 4 + t) * 512 + hh];
            float4 x1 = *(const float4*)&avred[(size_t)(1 * 4 + t) * 512 + hh];
            float4 r = make_float4(x0.x + x1.x, x0.y + x1.y, x0.z + x1.z, x0.w + x1.w);
            *(float4*)(out + ((size_t)b * TD + t0 + t) * HD + hh) = r;
        }
    }
}

// ================= fallback pair (proven R8 proj + R7 attn) =================
__global__ __launch_bounds__(256) void proj_fb(
    const float* __restrict__ enc, const float* __restrict__ qry,
    const float* __restrict__ Wh,  const float* __restrict__ Ws,
    float* __restrict__ encT, float* __restrict__ qryf)
{
    __shared__ _Float16 LA[64 * LSTR], LB[64 * LSTR];

    const int tid = threadIdx.x;
    const int l = tid & 63, w = tid >> 6;
    const int rf = l & 15, q = l >> 4;
    const int my = blockIdx.y;
    const bool isq = my >= 32;
    const int m0 = my * 64;
    const int n0 = blockIdx.x * 64;

    const int srow = tid >> 2;
    const int scol = (tid & 3) * 8;
    const float* Abase = isq
        ? qry + (size_t)(m0 - 2048 + srow) * HD + scol
        : enc + (size_t)(m0 + srow) * HD + scol;
    const float* Bbase = (isq ? Ws : Wh) + (size_t)(n0 + srow) * HD + scol;

    const int mi = (w & 1) * 32, ni = (w >> 1) * 32;
    float4v acc[2][2] = {{{0,0,0,0},{0,0,0,0}},{{0,0,0,0},{0,0,0,0}}};

    float4 a0 = *(const float4*)(Abase);
    float4 a1 = *(const float4*)(Abase + 4);
    float4 b0 = *(const float4*)(Bbase);
    float4 b1 = *(const float4*)(Bbase + 4);

    for (int ks = 0; ks < 16; ++ks) {
        if (ks) __syncthreads();
        {
            float af[8] = {a0.x,a0.y,a0.z,a0.w,a1.x,a1.y,a1.z,a1.w};
            float bf[8] = {b0.x,b0.y,b0.z,b0.w,b1.x,b1.y,b1.z,b1.w};
            half8 ha, hb;
            #pragma unroll
            for (int i = 0; i < 8; ++i) { ha[i] = (_Float16)af[i]; hb[i] = (_Float16)bf[i]; }
            *(half8*)&LA[srow * LSTR + scol] = ha;
            *(half8*)&LB[srow * LSTR + scol] = hb;
        }
        __syncthreads();
        if (ks + 1 < 16) {
            const int ko = (ks + 1) * 32;
            a0 = *(const float4*)(Abase + ko);
            a1 = *(const float4*)(Abase + ko + 4);
            b0 = *(const float4*)(Bbase + ko);
            b1 = *(const float4*)(Bbase + ko + 4);
        }
        half8 ah[2], bh[2];
        #pragma unroll
        for (int i = 0; i < 2; ++i) {
            ah[i] = *(const half8*)&LA[(mi + i * 16 + rf) * LSTR + q * 8];
            bh[i] = *(const half8*)&LB[(ni + i * 16 + rf) * LSTR + q * 8];
        }
        #pragma unroll
        for (int i = 0; i < 2; ++i)
            #pragma unroll
            for (int j = 0; j < 2; ++j)
                acc[i][j] = __builtin_amdgcn_mfma_f32_16x16x32_f16(ah[i], bh[j], acc[i][j], 0, 0, 0);
    }

    if (!isq) {
        const int b  = m0 >> 8;
        const int sb = (m0 & 255) + mi + q * 4;
        float* base = encT + (size_t)b * HD * SD;
        #pragma unroll
        for (int i = 0; i < 2; ++i)
            #pragma unroll
            for (int j = 0; j < 2; ++j) {
                float4 o = make_float4(exp2_sat(acc[i][j][0]*K2F), exp2_sat(acc[i][j][1]*K2F),
                                       exp2_sat(acc[i][j][2]*K2F), exp2_sat(acc[i][j][3]*K2F));
                *(float4*)(base + (size_t)(n0 + ni + j * 16 + rf) * SD + sb + i * 16) = o;
            }
    } else {
        const int mrow = (m0 - 2048) + mi + q * 4;
        #pragma unroll
        for (int i = 0; i < 2; ++i)
            #pragma unroll
            for (int j = 0; j < 2; ++j)
                #pragma unroll
                for (int r = 0; r < 4; ++r)
                    qryf[(size_t)(mrow + i * 16 + r) * HD + n0 + ni + j * 16 + rf] =
                        exp2_sat(acc[i][j][r] * K2F);
    }
}

__global__ __launch_bounds__(512) void attn_fb(
    const float* __restrict__ enc, const float* __restrict__ encT,
    const float* __restrict__ qryf, const float* __restrict__ v,
    const int* __restrict__ lens, float* __restrict__ out)
{
    __shared__ float qls[HD * 4];
    __shared__ float pls[8 * 4 * 256];
    __shared__ float wls[4 * SD];

    const int blk = blockIdx.x;
    const int b   = blk >> 6;
    const int t0  = (blk & 63) * 4;
    const int tid = threadIdx.x;
    const int w   = tid >> 6;
    const int l   = tid & 63;

    {
        const float* qf = qryf + ((size_t)b * TD + t0) * HD;
        float4 qv;
        qv.x = qf[0 * HD + tid]; qv.y = qf[1 * HD + tid];
        qv.z = qf[2 * HD + tid]; qv.w = qf[3 * HD + tid];
        *(float4*)&qls[tid * 4] = qv;
    }
    __syncthreads();

    float a[4][4];
    #pragma unroll
    for (int t = 0; t < 4; ++t)
        #pragma unroll
        for (int c = 0; c < 4; ++c) a[t][c] = 0.0f;
    {
        const float* ep = encT + (size_t)b * HD * SD + (size_t)(w * 64) * SD + l * 4;
        const int jbase = w * 64;
        #pragma unroll 4
        for (int jj = 0; jj < 64; ++jj) {
            float4 e = *(const float4*)(ep + (size_t)jj * SD);
            float4 q4 = *(const float4*)&qls[(jbase + jj) * 4];
            float vj = v[jbase + jj];
            float ev[4] = {e.x, e.y, e.z, e.w};
            float qv[4] = {q4.x, q4.y, q4.z, q4.w};
            #pragma unroll
            for (int t = 0; t < 4; ++t)
                #pragma unroll
                for (int c = 0; c < 4; ++c) {
                    float p = fmaf(ev[c], qv[t], 1.0f);
                    a[t][c] = fmaf(vj, RCP(p), a[t][c]);
                }
        }
    }
    #pragma unroll
    for (int t = 0; t < 4; ++t)
        *(float4*)&pls[(w * 4 + t) * 256 + l * 4] = make_float4(a[t][0], a[t][1], a[t][2], a[t][3]);
    __syncthreads();

    if (w < 4) {
        const int t = w;
        float p[4] = {0, 0, 0, 0};
        #pragma unroll
        for (int g = 0; g < 8; ++g) {
            float4 pp = *(const float4*)&pls[(g * 4 + t) * 256 + l * 4];
            p[0] += pp.x; p[1] += pp.y; p[2] += pp.z; p[3] += pp.w;
        }
        const int len = lens[b];
        const int s0 = l * 4;
        float sc[4];
        #pragma unroll
        for (int c = 0; c < 4; ++c)
            sc[c] = (s0 + c < len) ? -2.0f * p[c] : -INFINITY;
        float mx = fmaxf(fmaxf(sc[0], sc[1]), fmaxf(sc[2], sc[3]));
        #pragma unroll
        for (int off = 32; off; off >>= 1) mx = fmaxf(mx, __shfl_xor(mx, off));
        float ex[4]; float sum = 0.0f;
        #pragma unroll
        for (int c = 0; c < 4; ++c) { ex[c] = __expf(sc[c] - mx); sum += ex[c]; }
        #pragma unroll
        for (int off = 32; off; off >>= 1) sum += __shfl_xor(sum, off);
        const float inv = RCP(sum);
        *(float4*)&wls[t * SD + s0] = make_float4(ex[0]*inv, ex[1]*inv, ex[2]*inv, ex[3]*inv);
    }
    __syncthreads();

    const int g  = tid >> 7;
    const int h4 = (tid & 127) * 4;
    float* avred = pls;
    {
        const float* eb = enc + (size_t)b * SD * HD + h4;
        float4 o[4] = {{0,0,0,0},{0,0,0,0},{0,0,0,0},{0,0,0,0}};
        #pragma unroll 2
        for (int ss = 0; ss < 64; ++ss) {
            const int s = g * 64 + ss;
            float4 evv = *(const float4*)(eb + (size_t)s * HD);
            float wt[4];
            #pragma unroll
            for (int t = 0; t < 4; ++t) wt[t] = wls[t * SD + s];
            #pragma unroll
            for (int t = 0; t < 4; ++t) {
                o[t].x = fmaf(wt[t], evv.x, o[t].x);
                o[t].y = fmaf(wt[t], evv.y, o[t].y);
                o[t].z = fmaf(wt[t], evv.z, o[t].z);
                o[t].w = fmaf(wt[t], evv.w, o[t].w);
            }
        }
        #pragma unroll
        for (int t = 0; t < 4; ++t)
            *(float4*)&avred[(size_t)(g * 4 + t) * 512 + h4] = o[t];
    }
    __syncthreads();
    {
        const int t  = tid >> 7;
        const int hh = (tid & 127) * 4;
        float4 r = {0, 0, 0, 0};
        #pragma unroll
        for (int gg = 0; gg < 4; ++gg) {
            float4 x = *(const float4*)&avred[(size_t)(gg * 4 + t) * 512 + hh];
            r.x += x.x; r.y += x.y; r.z += x.z; r.w += x.w;
        }
        *(float4*)(out + ((size_t)b * TD + t0 + t) * HD + hh) = r;
    }
}

extern "C" void kernel_launch(void* const* d_in, const int* in_sizes, int n_in,
                              void* d_out, int out_size, void* d_ws, size_t ws_size,
                              hipStream_t stream) {
    const float* query = (const float*)d_in[0];
    const float* enc   = (const float*)d_in[1];
    const int*   lens  = (const int*)d_in[2];
    const float* W_h   = (const float*)d_in[3];
    const float* W_s   = (const float*)d_in[4];
    const float* v     = (const float*)d_in[5];
    float* out = (float*)d_out;

    char* ws = (char*)d_ws;
    float* encT = (float*)(ws);                       // 4 MB (B,H,S)  E_e
    float* qryf = (float*)(ws + ((size_t)4 << 20));   // 4 MB (B,T,H)  E_q

    // Host-side occupancy pre-screen (pure query — graph-safe, deterministic).
    int nb = 0;
    hipError_t oerr = hipOccupancyMaxActiveBlocksPerMultiprocessor(
        &nb, (const void*)fused_kernel, 512, 0);
    bool coop_ok = (oerr == hipSuccess) && (nb * 256 >= 512);

    if (coop_ok) {
        void* args[] = {
            (void*)&enc, (void*)&query, (void*)&W_h, (void*)&W_s,
            (void*)&v, (void*)&lens, (void*)&encT, (void*)&qryf, (void*)&out
        };
        hipError_t lerr = hipLaunchCooperativeKernel((const void*)fused_kernel,
                                                     dim3(512), dim3(512), args, 0, stream);
        if (lerr == hipSuccess) return;
    }

    // Fallback: proven two-kernel path.
    dim3 pgrid(HD / 64, 64);
    proj_fb<<<pgrid, 256, 0, stream>>>(enc, query, W_h, W_s, encT, qryf);
    attn_fb<<<BD * (TD / 4), 512, 0, stream>>>(enc, encT, qryf, v, lens, out);
}